// Round 1
// baseline (1523.063 us; speedup 1.0000x reference)
//
#include <hip/hip_runtime.h>
#include <hip/hip_bf16.h>

constexpr int cB = 4, cN = 8192, cC = 512, cH = 8, cD = 64;
constexpr int cM = cB * cN;        // 32768 tokens
constexpr int cHD = cH * cD;       // 512
constexpr int cBH = cB * cH;       // 32
constexpr float kEPS = 1e-6f;

// ---------------- f32 tiled GEMM: out = A[M x 512] @ W[ncols x 512]^T ----------------
// EPI=0: scatter qkv -> q=sigmoid, k=sigmoid, v*=0.125 in [B,H,N,D] layout
// EPI=1: out[m*512+col] = acc + bias[col]
template<int EPI>
__global__ __launch_bounds__(256) void gemm_k(
    const float* __restrict__ A, const float* __restrict__ Wm,
    const float* __restrict__ bias,
    float* __restrict__ o0, float* __restrict__ o1, float* __restrict__ o2) {
  constexpr int BM = 128, BN = 64, BK = 16;
  __shared__ float As[BM][BK + 1];
  __shared__ float Bs[BK][BN + 1];
  const int t = threadIdx.x;
  const int row0 = blockIdx.x * BM;
  const int col0 = blockIdx.y * BN;
  const int tx = t & 15, ty = t >> 4;   // 16x16 threads, 8x4 micro-tile
  float acc[8][4] = {};
  for (int k0 = 0; k0 < cC; k0 += BK) {
    #pragma unroll
    for (int u = 0; u < 2; ++u) {
      const int id = t * 2 + u;               // 0..511 float4 loads
      const int r = id >> 2, c4 = (id & 3) << 2;
      const float4 val = *reinterpret_cast<const float4*>(&A[(size_t)(row0 + r) * cC + k0 + c4]);
      As[r][c4 + 0] = val.x; As[r][c4 + 1] = val.y;
      As[r][c4 + 2] = val.z; As[r][c4 + 3] = val.w;
    }
    #pragma unroll
    for (int u = 0; u < 4; ++u) {
      const int id = t + u * 256;             // 0..1023
      const int c = id & 15, j = id >> 4;     // coalesced along W rows
      Bs[c][j] = Wm[(size_t)(col0 + j) * cC + k0 + c];
    }
    __syncthreads();
    #pragma unroll
    for (int kk = 0; kk < BK; ++kk) {
      float a[8], bv[4];
      #pragma unroll
      for (int i = 0; i < 8; ++i) a[i] = As[ty * 8 + i][kk];
      #pragma unroll
      for (int j = 0; j < 4; ++j) bv[j] = Bs[kk][tx * 4 + j];
      #pragma unroll
      for (int i = 0; i < 8; ++i)
        #pragma unroll
        for (int j = 0; j < 4; ++j)
          acc[i][j] = fmaf(a[i], bv[j], acc[i][j]);
    }
    __syncthreads();
  }
  #pragma unroll
  for (int i = 0; i < 8; ++i) {
    const int m = row0 + ty * 8 + i;
    const int bb = m >> 13;                   // m / 8192
    const int n = m & 8191;
    #pragma unroll
    for (int j = 0; j < 4; ++j) {
      const int col = col0 + tx * 4 + j;
      const float val = acc[i][j];
      if (EPI == 0) {
        const int which = col >> 9;           // 0=q 1=k 2=v
        const int c2 = col & 511;
        const int h = c2 >> 6, d = c2 & 63;
        const size_t idx = (((size_t)(bb * cH + h)) * cN + n) * cD + d;
        if (which == 0)      o0[idx] = 1.f / (1.f + __expf(-val));
        else if (which == 1) o1[idx] = 1.f / (1.f + __expf(-val));
        else                 o2[idx] = val * 0.125f;   // v / 8.0
      } else {
        o0[(size_t)m * cC + col] = val + bias[col];
      }
    }
  }
}

// ---------------- K2: k_sum, q_sum over N ----------------
__global__ __launch_bounds__(256) void k2_sums(const float* __restrict__ q,
      const float* __restrict__ k, float* __restrict__ qsum, float* __restrict__ ksum) {
  const int bh = blockIdx.x;                 // 32
  constexpr int ROWS = cN / 16;              // grid.y = 16 -> 512 rows/block
  const int r0 = blockIdx.y * ROWS;
  const int t = threadIdx.x;
  const int d = t & 63, rr = t >> 6;
  const float* qb = q + (size_t)bh * cN * cD;
  const float* kb = k + (size_t)bh * cN * cD;
  float aq = 0.f, ak = 0.f;
  for (int r = r0 + rr; r < r0 + ROWS; r += 4) {
    aq += qb[(size_t)r * cD + d];
    ak += kb[(size_t)r * cD + d];
  }
  __shared__ float sq[4][64], sk[4][64];
  sq[rr][d] = aq; sk[rr][d] = ak;
  __syncthreads();
  if (t < 64) {
    atomicAdd(&qsum[bh * 64 + t], sq[0][t] + sq[1][t] + sq[2][t] + sq[3][t]);
    atomicAdd(&ksum[bh * 64 + t], sk[0][t] + sk[1][t] + sk[2][t] + sk[3][t]);
  }
}

// ---------------- K3: sink_incoming, source_outgoing; S_q, S_k ----------------
__global__ __launch_bounds__(256) void k3_flow1(const float* __restrict__ q,
      const float* __restrict__ k, const float* __restrict__ qsum,
      const float* __restrict__ ksum, float* __restrict__ si,
      float* __restrict__ Sq, float* __restrict__ Sk) {
  const int bh = blockIdx.x;
  const int n0 = blockIdx.y * 64;
  const int lane = threadIdx.x & 63;
  const int wave = threadIdx.x >> 6;
  const float* qb = q + (size_t)bh * cN * cD;
  const float* kb = k + (size_t)bh * cN * cD;
  const float ksd = ksum[bh * 64 + lane] + kEPS;
  const float qsd = qsum[bh * 64 + lane] + kEPS;
  float aSq = 0.f, aSk = 0.f;
  for (int i = 0; i < 16; ++i) {
    const int n = n0 + wave * 16 + i;
    const float qd = qb[(size_t)n * cD + lane];
    const float kd = kb[(size_t)n * cD + lane];
    float t1 = (qd + kEPS) * ksd;
    float t2 = (kd + kEPS) * qsd;
    #pragma unroll
    for (int off = 32; off; off >>= 1) {
      t1 += __shfl_xor(t1, off);
      t2 += __shfl_xor(t2, off);
    }
    const float si_n = 1.f / (t1 + kEPS);    // sink_incoming
    const float so_n = 1.f / (t2 + kEPS);    // source_outgoing
    if (lane == 0) si[(size_t)bh * cN + n] = si_n;
    aSq = fmaf(qd, si_n, aSq);
    aSk = fmaf(kd, so_n, aSk);
  }
  __shared__ float sA[4][64], sB[4][64];
  sA[wave][lane] = aSq; sB[wave][lane] = aSk;
  __syncthreads();
  if (threadIdx.x < 64) {
    const int d = threadIdx.x;
    atomicAdd(&Sq[bh * 64 + d], sA[0][d] + sA[1][d] + sA[2][d] + sA[3][d]);
    atomicAdd(&Sk[bh * 64 + d], sB[0][d] + sB[1][d] + sB[2][d] + sB[3][d]);
  }
}

// ---------------- K4: conserved_source/sink -> ev, Z, sink_allocation ----------------
__global__ __launch_bounds__(256) void k4_flow2(const float* __restrict__ q,
      const float* __restrict__ k, const float* __restrict__ Sq,
      const float* __restrict__ Sk, float* __restrict__ ev,
      float* __restrict__ sa, float* __restrict__ Zb) {
  const int bh = blockIdx.x;
  const int n0 = blockIdx.y * 64;
  const int lane = threadIdx.x & 63;
  const int wave = threadIdx.x >> 6;
  const float* qb = q + (size_t)bh * cN * cD;
  const float* kb = k + (size_t)bh * cN * cD;
  const float sqd = Sq[bh * 64 + lane] + kEPS;
  const float skd = Sk[bh * 64 + lane] + kEPS;
  float aZ = 0.f;
  for (int i = 0; i < 16; ++i) {
    const int n = n0 + wave * 16 + i;
    const float qd = qb[(size_t)n * cD + lane];
    const float kd = kb[(size_t)n * cD + lane];
    float t1 = (kd + kEPS) * sqd;   // conserved_source terms
    float t2 = (qd + kEPS) * skd;   // conserved_sink terms
    #pragma unroll
    for (int off = 32; off; off >>= 1) {
      t1 += __shfl_xor(t1, off);
      t2 += __shfl_xor(t2, off);
    }
    float cs = t1 + kEPS;
    cs = fminf(fmaxf(cs, -1.f), 1.f);        // clip
    const float e = __expf(cs);              // softmax numerator (x in [-1,1], no max-sub needed)
    const float sank = 1.f / (1.f + __expf(-(t2 + kEPS)));  // sigmoid(cs_sink * 1.0)
    if (lane == 0) {
      ev[(size_t)bh * cN + n] = e;
      sa[(size_t)bh * cN + n] = sank;
      aZ += e;
    }
  }
  __shared__ float sZ[4];
  if (lane == 0) sZ[wave] = aZ;
  __syncthreads();
  if (threadIdx.x == 0) atomicAdd(&Zb[bh], sZ[0] + sZ[1] + sZ[2] + sZ[3]);
}

// ---------------- K5: kv[b,h,d,e] = sum_n k[n,d] * v[n,e]*comp[n] ----------------
__global__ __launch_bounds__(256) void k5_kv(const float* __restrict__ kk_,
      const float* __restrict__ vv, const float* __restrict__ ev,
      const float* __restrict__ Zb, float* __restrict__ kvout) {
  const int bh = blockIdx.x;                 // 32
  constexpr int ROWS = cN / 16;              // grid.y = 16 -> 512 rows
  const int n0 = blockIdx.y * ROWS;
  const int t = threadIdx.x;
  const int d = t & 63;
  const int eb = t >> 6;                     // 4 e-blocks of 16
  const float* kb = kk_ + (size_t)bh * cN * cD;
  const float* vb = vv + (size_t)bh * cN * cD;
  const float zs = (float)cN / Zb[bh];       // softmax * N
  __shared__ float ks[8][64];
  __shared__ float vs[8][64];
  float acc[16] = {};
  for (int r0 = 0; r0 < ROWS; r0 += 8) {
    __syncthreads();
    {
      const int r = t >> 6, c = t & 63;      // 4 rows x 64 cols, twice
      ks[r][c]     = kb[(size_t)(n0 + r0 + r) * cD + c];
      ks[r + 4][c] = kb[(size_t)(n0 + r0 + r + 4) * cD + c];
      const float e0 = ev[(size_t)bh * cN + n0 + r0 + r] * zs;
      const float e1 = ev[(size_t)bh * cN + n0 + r0 + r + 4] * zs;
      vs[r][c]     = vb[(size_t)(n0 + r0 + r) * cD + c] * e0;
      vs[r + 4][c] = vb[(size_t)(n0 + r0 + r + 4) * cD + c] * e1;
    }
    __syncthreads();
    #pragma unroll
    for (int r = 0; r < 8; ++r) {
      const float kd = ks[r][d];
      #pragma unroll
      for (int j = 0; j < 16; ++j)
        acc[j] = fmaf(kd, vs[r][eb * 16 + j], acc[j]);
    }
  }
  float* kvb = kvout + (size_t)bh * cD * cD + (size_t)d * cD + eb * 16;
  #pragma unroll
  for (int j = 0; j < 16; ++j) atomicAdd(&kvb[j], acc[j]);
}

// ---------------- K6a: x_update = (q @ kv) * si * sa, layout [B,N,H,D] ----------------
__global__ __launch_bounds__(256) void k6a_xu(const float* __restrict__ q,
      const float* __restrict__ kvmat, const float* __restrict__ si,
      const float* __restrict__ sa, float* __restrict__ xu) {
  const int bh = blockIdx.x;
  const int b = bh >> 3, h = bh & 7;
  const int n0 = blockIdx.y * 64;
  const int lane = threadIdx.x & 63;        // output e
  const int wave = threadIdx.x >> 6;
  __shared__ float kvs[64][64];
  for (int i = threadIdx.x; i < 4096; i += 256)
    kvs[i >> 6][i & 63] = kvmat[(size_t)bh * 4096 + i];
  __syncthreads();
  const float* qb = q + (size_t)bh * cN * cD;
  for (int i = 0; i < 16; ++i) {
    const int n = n0 + wave * 16 + i;
    const float qd = qb[(size_t)n * cD + lane];   // lane as d for load
    float acc = 0.f;
    #pragma unroll
    for (int dd = 0; dd < 64; ++dd) {
      const float qv = __shfl(qd, dd);
      acc = fmaf(qv, kvs[dd][lane], acc);
    }
    const float s = si[(size_t)bh * cN + n] * sa[(size_t)bh * cN + n];
    xu[(((size_t)b * cN + n) * cH + h) * cD + lane] = acc * s;
  }
}

extern "C" void kernel_launch(void* const* d_in, const int* in_sizes, int n_in,
                              void* d_out, int out_size, void* d_ws, size_t ws_size,
                              hipStream_t stream) {
  (void)in_sizes; (void)n_in; (void)out_size;
  const float* x     = (const float*)d_in[0];
  const float* Wqkv  = (const float*)d_in[1];
  const float* Wproj = (const float*)d_in[2];
  const float* bproj = (const float*)d_in[3];
  float* out = (float*)d_out;
  float* ws  = (float*)d_ws;

  const size_t SLAB = (size_t)cBH * cN * cD;       // 16,777,216 floats (64 MB)
  const size_t OFF_Q   = 0;
  const size_t OFF_K   = SLAB;
  const size_t OFF_V   = 2 * SLAB;                 // xu aliases v (v dead after K5)
  const size_t OFF_ACC = 3 * SLAB;
  const size_t ACC_FLOATS = 2048 * 4 + 32 + (size_t)cBH * cD * cD;  // 139,296
  const size_t OFF_SI  = OFF_ACC + ACC_FLOATS;
  const size_t OFF_SA  = OFF_SI + (size_t)cBH * cN;
  const size_t OFF_EV  = OFF_SA + (size_t)cBH * cN;
  const size_t TOTAL   = OFF_EV + (size_t)cBH * cN;  // ~51.3M floats (~196 MiB)
  if (ws_size < TOTAL * sizeof(float)) return;       // fail loudly (wrong output) if ws too small

  float* q    = ws + OFF_Q;
  float* k    = ws + OFF_K;
  float* v    = ws + OFF_V;
  float* xu   = ws + OFF_V;   // alias
  float* ksum = ws + OFF_ACC;
  float* qsum = ksum + 2048;
  float* Sk   = ksum + 4096;
  float* Sq   = ksum + 6144;
  float* Zb   = ksum + 8192;
  float* kvm  = ksum + 8224;
  float* si   = ws + OFF_SI;
  float* sa   = ws + OFF_SA;
  float* ev   = ws + OFF_EV;

  hipMemsetAsync(ksum, 0, ACC_FLOATS * sizeof(float), stream);

  gemm_k<0><<<dim3(cM / 128, (3 * cHD) / 64), 256, 0, stream>>>(x, Wqkv, nullptr, q, k, v);
  k2_sums<<<dim3(cBH, 16), 256, 0, stream>>>(q, k, qsum, ksum);
  k3_flow1<<<dim3(cBH, cN / 64), 256, 0, stream>>>(q, k, qsum, ksum, si, Sq, Sk);
  k4_flow2<<<dim3(cBH, cN / 64), 256, 0, stream>>>(q, k, Sq, Sk, ev, sa, Zb);
  k5_kv<<<dim3(cBH, 16), 256, 0, stream>>>(k, v, ev, Zb, kvm);
  k6a_xu<<<dim3(cBH, cN / 64), 256, 0, stream>>>(q, kvm, si, sa, xu);
  gemm_k<1><<<dim3(cM / 128, cHD / 64), 256, 0, stream>>>(xu, Wproj, bproj, out, nullptr, nullptr);
}

// Round 2
// 712.775 us; speedup vs baseline: 2.1368x; 2.1368x over previous
//
#include <hip/hip_runtime.h>
#include <hip/hip_bf16.h>

typedef __attribute__((ext_vector_type(8))) short short8;
typedef __attribute__((ext_vector_type(4))) float f32x4;

constexpr int cB = 4, cN = 8192, cC = 512, cH = 8, cD = 64;
constexpr int cM = cB * cN;        // 32768 tokens
constexpr int cHD = cH * cD;       // 512
constexpr int cBH = cB * cH;       // 32
constexpr float kEPS = 1e-6f;

// ---- split f32 -> (bf16 hi by truncation, bf16 lo of remainder) ----
__device__ __forceinline__ void split2(float f, ushort& h, ushort& l) {
  unsigned u = __float_as_uint(f);
  h = (ushort)(u >> 16);
  float fl = f - __uint_as_float(u & 0xffff0000u);
  l = (ushort)(__float_as_uint(fl) >> 16);
}
__device__ __forceinline__ int pack_hi(float a, float b) {
  return (int)((__float_as_uint(a) >> 16) | (__float_as_uint(b) & 0xffff0000u));
}
__device__ __forceinline__ int pack_lo(float a, float b) {
  float la = a - __uint_as_float(__float_as_uint(a) & 0xffff0000u);
  float lb = b - __uint_as_float(__float_as_uint(b) & 0xffff0000u);
  return (int)((__float_as_uint(la) >> 16) | (__float_as_uint(lb) & 0xffff0000u));
}

// ---------------- W splitter: f32 -> bf16 hi/lo ----------------
__global__ __launch_bounds__(256) void split_w(const float* __restrict__ src,
    ushort* __restrict__ hi, ushort* __restrict__ lo, int n4) {
  int i = blockIdx.x * 256 + threadIdx.x;
  if (i >= n4) return;
  float4 v = reinterpret_cast<const float4*>(src)[i];
  ushort4 h, l;
  split2(v.x, h.x, l.x); split2(v.y, h.y, l.y);
  split2(v.z, h.z, l.z); split2(v.w, h.w, l.w);
  reinterpret_cast<ushort4*>(hi)[i] = h;
  reinterpret_cast<ushort4*>(lo)[i] = l;
}

// ---------------- split-bf16 MFMA GEMM: C = A[Mx512] @ W[NCx512]^T ----------------
// A f32 reg-staged + converted; W pre-split bf16 staged via global_load_lds.
// EPI=0: scatter qkv (sigmoid q,k; v*0.125) -> [B,H,N,D] slabs. EPI=1: out + bias.
template<int EPI>
__global__ __launch_bounds__(256) void gemm_mfma(
    const float* __restrict__ A,
    const ushort* __restrict__ Wh, const ushort* __restrict__ Wl,
    const float* __restrict__ bias,
    float* __restrict__ o0, float* __restrict__ o1, float* __restrict__ o2) {
  constexpr int BM = 128, BN = 128, BK = 32;
  constexpr int LDA = 40;                      // padded bf16 stride (80 B) -> conflict-free
  __shared__ ushort Ah[BM * LDA], Al[BM * LDA];
  __shared__ ushort Bh[BN * 32], Bl[BN * 32];  // linear (global_load_lds requirement)
  const int t = threadIdx.x;
  const int wave = t >> 6, lane = t & 63;
  const int wm = wave >> 1, wn = wave & 1;     // 2x2 waves of 64x64
  const int row0 = blockIdx.x * BM, col0 = blockIdx.y * BN;
  const int l15 = lane & 15, lg = lane >> 4;

  f32x4 acc[4][4] = {};

  const int arow = t >> 1, akh = (t & 1) * 16;           // A-stage mapping
  const float* aptr = A + (size_t)(row0 + arow) * cC + akh;
  const int brr = lane >> 2, bg = lane & 3;              // B-stage lane mapping

  for (int k0 = 0; k0 < cC; k0 += BK) {
    __syncthreads();
    // ---- stage A: 16 f32 -> bf16 hi/lo, padded LDS ----
    {
      const float4 fa = *(const float4*)(aptr + k0 + 0);
      const float4 fb = *(const float4*)(aptr + k0 + 4);
      const float4 fc = *(const float4*)(aptr + k0 + 8);
      const float4 fd = *(const float4*)(aptr + k0 + 12);
      int4 H0 = make_int4(pack_hi(fa.x, fa.y), pack_hi(fa.z, fa.w),
                          pack_hi(fb.x, fb.y), pack_hi(fb.z, fb.w));
      int4 H1 = make_int4(pack_hi(fc.x, fc.y), pack_hi(fc.z, fc.w),
                          pack_hi(fd.x, fd.y), pack_hi(fd.z, fd.w));
      int4 L0 = make_int4(pack_lo(fa.x, fa.y), pack_lo(fa.z, fa.w),
                          pack_lo(fb.x, fb.y), pack_lo(fb.z, fb.w));
      int4 L1 = make_int4(pack_lo(fc.x, fc.y), pack_lo(fc.z, fc.w),
                          pack_lo(fd.x, fd.y), pack_lo(fd.z, fd.w));
      *reinterpret_cast<int4*>(&Ah[arow * LDA + akh]) = H0;
      *reinterpret_cast<int4*>(&Ah[arow * LDA + akh + 8]) = H1;
      *reinterpret_cast<int4*>(&Al[arow * LDA + akh]) = L0;
      *reinterpret_cast<int4*>(&Al[arow * LDA + akh + 8]) = L1;
    }
    // ---- stage B: global_load_lds dwordx4, hi & lo, two 16-row halves ----
    #pragma unroll
    for (int hh = 0; hh < 2; ++hh) {
      const int br = wave * 32 + hh * 16 + brr;
      const size_t goff = (size_t)(col0 + br) * cC + k0 + bg * 8;
      __builtin_amdgcn_global_load_lds(
          (const __attribute__((address_space(1))) void*)(Wh + goff),
          (__attribute__((address_space(3))) void*)(&Bh[(wave * 32 + hh * 16) * 32]),
          16, 0, 0);
      __builtin_amdgcn_global_load_lds(
          (const __attribute__((address_space(1))) void*)(Wl + goff),
          (__attribute__((address_space(3))) void*)(&Bl[(wave * 32 + hh * 16) * 32]),
          16, 0, 0);
    }
    __syncthreads();
    // ---- fragments + 3-product MFMA ----
    short8 ah[4], al[4];
    #pragma unroll
    for (int mi = 0; mi < 4; ++mi) {
      const int r = wm * 64 + mi * 16 + l15;
      ah[mi] = *reinterpret_cast<const short8*>(&Ah[r * LDA + lg * 8]);
      al[mi] = *reinterpret_cast<const short8*>(&Al[r * LDA + lg * 8]);
    }
    #pragma unroll
    for (int ni = 0; ni < 4; ++ni) {
      const int c = wn * 64 + ni * 16 + l15;
      const short8 bh = *reinterpret_cast<const short8*>(&Bh[c * 32 + lg * 8]);
      const short8 bl = *reinterpret_cast<const short8*>(&Bl[c * 32 + lg * 8]);
      #pragma unroll
      for (int mi = 0; mi < 4; ++mi) {
        acc[mi][ni] = __builtin_amdgcn_mfma_f32_16x16x32_bf16(ah[mi], bh, acc[mi][ni], 0, 0, 0);
        acc[mi][ni] = __builtin_amdgcn_mfma_f32_16x16x32_bf16(al[mi], bh, acc[mi][ni], 0, 0, 0);
        acc[mi][ni] = __builtin_amdgcn_mfma_f32_16x16x32_bf16(ah[mi], bl, acc[mi][ni], 0, 0, 0);
      }
    }
  }
  // ---- epilogue: C/D map col=lane&15, row=(lane>>4)*4+r ----
  #pragma unroll
  for (int mi = 0; mi < 4; ++mi) {
    #pragma unroll
    for (int ni = 0; ni < 4; ++ni) {
      const int col = col0 + wn * 64 + ni * 16 + l15;
      #pragma unroll
      for (int r = 0; r < 4; ++r) {
        const int m = row0 + wm * 64 + mi * 16 + lg * 4 + r;
        const float val = acc[mi][ni][r];
        if (EPI == 0) {
          const int which = col >> 9;
          const int c2 = col & 511;
          const int h = c2 >> 6, d = c2 & 63;
          const int bb = m >> 13, n = m & 8191;
          const size_t idx = (((size_t)(bb * cH + h)) * cN + n) * cD + d;
          if (which == 0)      o0[idx] = 1.f / (1.f + __expf(-val));
          else if (which == 1) o1[idx] = 1.f / (1.f + __expf(-val));
          else                 o2[idx] = val * 0.125f;
        } else {
          o0[(size_t)m * cC + col] = val + bias[col];
        }
      }
    }
  }
}

// ---------------- K2: k_sum, q_sum over N ----------------
__global__ __launch_bounds__(256) void k2_sums(const float* __restrict__ q,
      const float* __restrict__ k, float* __restrict__ qsum, float* __restrict__ ksum) {
  const int bh = blockIdx.x;
  constexpr int ROWS = cN / 16;
  const int r0 = blockIdx.y * ROWS;
  const int t = threadIdx.x;
  const int d = t & 63, rr = t >> 6;
  const float* qb = q + (size_t)bh * cN * cD;
  const float* kb = k + (size_t)bh * cN * cD;
  float aq = 0.f, ak = 0.f;
  for (int r = r0 + rr; r < r0 + ROWS; r += 4) {
    aq += qb[(size_t)r * cD + d];
    ak += kb[(size_t)r * cD + d];
  }
  __shared__ float sq[4][64], sk[4][64];
  sq[rr][d] = aq; sk[rr][d] = ak;
  __syncthreads();
  if (t < 64) {
    atomicAdd(&qsum[bh * 64 + t], sq[0][t] + sq[1][t] + sq[2][t] + sq[3][t]);
    atomicAdd(&ksum[bh * 64 + t], sk[0][t] + sk[1][t] + sk[2][t] + sk[3][t]);
  }
}

// ---------------- K3: sink_incoming, source_outgoing; S_q, S_k ----------------
__global__ __launch_bounds__(256) void k3_flow1(const float* __restrict__ q,
      const float* __restrict__ k, const float* __restrict__ qsum,
      const float* __restrict__ ksum, float* __restrict__ si,
      float* __restrict__ Sq, float* __restrict__ Sk) {
  const int bh = blockIdx.x;
  const int n0 = blockIdx.y * 64;
  const int lane = threadIdx.x & 63;
  const int wave = threadIdx.x >> 6;
  const float* qb = q + (size_t)bh * cN * cD;
  const float* kb = k + (size_t)bh * cN * cD;
  const float ksd = ksum[bh * 64 + lane] + kEPS;
  const float qsd = qsum[bh * 64 + lane] + kEPS;
  float aSq = 0.f, aSk = 0.f;
  for (int i = 0; i < 16; ++i) {
    const int n = n0 + wave * 16 + i;
    const float qd = qb[(size_t)n * cD + lane];
    const float kd = kb[(size_t)n * cD + lane];
    float t1 = (qd + kEPS) * ksd;
    float t2 = (kd + kEPS) * qsd;
    #pragma unroll
    for (int off = 32; off; off >>= 1) {
      t1 += __shfl_xor(t1, off);
      t2 += __shfl_xor(t2, off);
    }
    const float si_n = 1.f / (t1 + kEPS);
    const float so_n = 1.f / (t2 + kEPS);
    if (lane == 0) si[(size_t)bh * cN + n] = si_n;
    aSq = fmaf(qd, si_n, aSq);
    aSk = fmaf(kd, so_n, aSk);
  }
  __shared__ float sA[4][64], sB[4][64];
  sA[wave][lane] = aSq; sB[wave][lane] = aSk;
  __syncthreads();
  if (threadIdx.x < 64) {
    const int d = threadIdx.x;
    atomicAdd(&Sq[bh * 64 + d], sA[0][d] + sA[1][d] + sA[2][d] + sA[3][d]);
    atomicAdd(&Sk[bh * 64 + d], sB[0][d] + sB[1][d] + sB[2][d] + sB[3][d]);
  }
}

// ---------------- K4: conserved flows -> ev, Z, sink_allocation ----------------
__global__ __launch_bounds__(256) void k4_flow2(const float* __restrict__ q,
      const float* __restrict__ k, const float* __restrict__ Sq,
      const float* __restrict__ Sk, float* __restrict__ ev,
      float* __restrict__ sa, float* __restrict__ Zb) {
  const int bh = blockIdx.x;
  const int n0 = blockIdx.y * 64;
  const int lane = threadIdx.x & 63;
  const int wave = threadIdx.x >> 6;
  const float* qb = q + (size_t)bh * cN * cD;
  const float* kb = k + (size_t)bh * cN * cD;
  const float sqd = Sq[bh * 64 + lane] + kEPS;
  const float skd = Sk[bh * 64 + lane] + kEPS;
  float aZ = 0.f;
  for (int i = 0; i < 16; ++i) {
    const int n = n0 + wave * 16 + i;
    const float qd = qb[(size_t)n * cD + lane];
    const float kd = kb[(size_t)n * cD + lane];
    float t1 = (kd + kEPS) * sqd;
    float t2 = (qd + kEPS) * skd;
    #pragma unroll
    for (int off = 32; off; off >>= 1) {
      t1 += __shfl_xor(t1, off);
      t2 += __shfl_xor(t2, off);
    }
    float cs = t1 + kEPS;
    cs = fminf(fmaxf(cs, -1.f), 1.f);
    const float e = __expf(cs);
    const float sank = 1.f / (1.f + __expf(-(t2 + kEPS)));
    if (lane == 0) {
      ev[(size_t)bh * cN + n] = e;
      sa[(size_t)bh * cN + n] = sank;
      aZ += e;
    }
  }
  __shared__ float sZ[4];
  if (lane == 0) sZ[wave] = aZ;
  __syncthreads();
  if (threadIdx.x == 0) atomicAdd(&Zb[bh], sZ[0] + sZ[1] + sZ[2] + sZ[3]);
}

// ---------------- K5: kv[b,h,d,e] = sum_n k[n,d] * v[n,e]*comp[n] ----------------
__global__ __launch_bounds__(256) void k5_kv(const float* __restrict__ kk_,
      const float* __restrict__ vv, const float* __restrict__ ev,
      const float* __restrict__ Zb, float* __restrict__ kvout) {
  const int bh = blockIdx.x;
  constexpr int ROWS = cN / 16;
  const int n0 = blockIdx.y * ROWS;
  const int t = threadIdx.x;
  const int d = t & 63;
  const int eb = t >> 6;
  const float* kb = kk_ + (size_t)bh * cN * cD;
  const float* vb = vv + (size_t)bh * cN * cD;
  const float zs = (float)cN / Zb[bh];
  __shared__ float ks[8][64];
  __shared__ float vs[8][64];
  float acc[16] = {};
  for (int r0 = 0; r0 < ROWS; r0 += 8) {
    __syncthreads();
    {
      const int r = t >> 6, c = t & 63;
      ks[r][c]     = kb[(size_t)(n0 + r0 + r) * cD + c];
      ks[r + 4][c] = kb[(size_t)(n0 + r0 + r + 4) * cD + c];
      const float e0 = ev[(size_t)bh * cN + n0 + r0 + r] * zs;
      const float e1 = ev[(size_t)bh * cN + n0 + r0 + r + 4] * zs;
      vs[r][c]     = vb[(size_t)(n0 + r0 + r) * cD + c] * e0;
      vs[r + 4][c] = vb[(size_t)(n0 + r0 + r + 4) * cD + c] * e1;
    }
    __syncthreads();
    #pragma unroll
    for (int r = 0; r < 8; ++r) {
      const float kd = ks[r][d];
      #pragma unroll
      for (int j = 0; j < 16; ++j)
        acc[j] = fmaf(kd, vs[r][eb * 16 + j], acc[j]);
    }
  }
  float* kvb = kvout + (size_t)bh * cD * cD + (size_t)d * cD + eb * 16;
  #pragma unroll
  for (int j = 0; j < 16; ++j) atomicAdd(&kvb[j], acc[j]);
}

// ---------------- K6a: x_update = (q @ kv) * si * sa, layout [B,N,H,D] ----------------
__global__ __launch_bounds__(256) void k6a_xu(const float* __restrict__ q,
      const float* __restrict__ kvmat, const float* __restrict__ si,
      const float* __restrict__ sa, float* __restrict__ xu) {
  const int bh = blockIdx.x;
  const int b = bh >> 3, h = bh & 7;
  const int n0 = blockIdx.y * 64;
  const int lane = threadIdx.x & 63;
  const int wave = threadIdx.x >> 6;
  __shared__ float kvs[64][64];
  for (int i = threadIdx.x; i < 4096; i += 256)
    kvs[i >> 6][i & 63] = kvmat[(size_t)bh * 4096 + i];
  __syncthreads();
  const float* qb = q + (size_t)bh * cN * cD;
  for (int i = 0; i < 16; ++i) {
    const int n = n0 + wave * 16 + i;
    const float qd = qb[(size_t)n * cD + lane];
    float acc = 0.f;
    #pragma unroll
    for (int dd = 0; dd < 64; ++dd) {
      const float qv = __shfl(qd, dd);
      acc = fmaf(qv, kvs[dd][lane], acc);
    }
    const float s = si[(size_t)bh * cN + n] * sa[(size_t)bh * cN + n];
    xu[(((size_t)b * cN + n) * cH + h) * cD + lane] = acc * s;
  }
}

extern "C" void kernel_launch(void* const* d_in, const int* in_sizes, int n_in,
                              void* d_out, int out_size, void* d_ws, size_t ws_size,
                              hipStream_t stream) {
  (void)in_sizes; (void)n_in; (void)out_size;
  const float* x     = (const float*)d_in[0];
  const float* Wqkv  = (const float*)d_in[1];
  const float* Wproj = (const float*)d_in[2];
  const float* bproj = (const float*)d_in[3];
  float* out = (float*)d_out;
  float* ws  = (float*)d_ws;

  const size_t SLAB = (size_t)cBH * cN * cD;       // 16,777,216 floats
  const size_t OFF_Q   = 0;
  const size_t OFF_K   = SLAB;
  const size_t OFF_V   = 2 * SLAB;                 // xu aliases v (v dead after K5)
  const size_t OFF_ACC = 3 * SLAB;
  const size_t ACC_FLOATS = 2048 * 4 + 32 + (size_t)cBH * cD * cD;
  const size_t OFF_SI  = OFF_ACC + ACC_FLOATS;
  const size_t OFF_SA  = OFF_SI + (size_t)cBH * cN;
  const size_t OFF_EV  = OFF_SA + (size_t)cBH * cN;
  const size_t TOTAL   = OFF_EV + (size_t)cBH * cN;  // same as round 1 (~196 MiB)
  if (ws_size < TOTAL * sizeof(float)) return;

  float* q    = ws + OFF_Q;
  float* k    = ws + OFF_K;
  float* v    = ws + OFF_V;
  float* xu   = ws + OFF_V;   // alias
  float* ksum = ws + OFF_ACC;
  float* qsum = ksum + 2048;
  float* Sk   = ksum + 4096;
  float* Sq   = ksum + 6144;
  float* Zb   = ksum + 8192;
  float* kvm  = ksum + 8224;
  float* si   = ws + OFF_SI;
  float* sa   = ws + OFF_SA;
  float* ev   = ws + OFF_EV;

  // W splits alias si/sa/ev (si/sa/ev are written only later by k3/k4;
  // wq splits dead after gemm<0>; wp splits created after k6a, dead after gemm<1>)
  ushort* wqh = (ushort*)(ws + OFF_SI);            // 786432 ushorts (1.5 MB)
  ushort* wql = wqh + (size_t)3 * cHD * cC;        // 786432 ushorts
  ushort* wph = (ushort*)(ws + OFF_SI);            // 262144 ushorts
  ushort* wpl = wph + (size_t)cC * cHD;            // 262144 ushorts

  hipMemsetAsync(ksum, 0, ACC_FLOATS * sizeof(float), stream);

  split_w<<<(3 * cHD * cC / 4 + 255) / 256, 256, 0, stream>>>(Wqkv, wqh, wql, 3 * cHD * cC / 4);
  gemm_mfma<0><<<dim3(cM / 128, (3 * cHD) / 128), 256, 0, stream>>>(x, wqh, wql, nullptr, q, k, v);
  k2_sums<<<dim3(cBH, 16), 256, 0, stream>>>(q, k, qsum, ksum);
  k3_flow1<<<dim3(cBH, cN / 64), 256, 0, stream>>>(q, k, qsum, ksum, si, Sq, Sk);
  k4_flow2<<<dim3(cBH, cN / 64), 256, 0, stream>>>(q, k, Sq, Sk, ev, sa, Zb);
  k5_kv<<<dim3(cBH, 16), 256, 0, stream>>>(k, v, ev, Zb, kvm);
  k6a_xu<<<dim3(cBH, cN / 64), 256, 0, stream>>>(q, kvm, si, sa, xu);
  split_w<<<(cC * cHD / 4 + 255) / 256, 256, 0, stream>>>(Wproj, wph, wpl, cC * cHD / 4);
  gemm_mfma<1><<<dim3(cM / 128, cHD / 128), 256, 0, stream>>>(xu, wph, wpl, bproj, out, nullptr, nullptr);
}

// Round 3
// 635.765 us; speedup vs baseline: 2.3956x; 1.1211x over previous
//
#include <hip/hip_runtime.h>
#include <hip/hip_bf16.h>

typedef __attribute__((ext_vector_type(8))) short short8;
typedef __attribute__((ext_vector_type(4))) float f32x4;

constexpr int cB = 4, cN = 8192, cC = 512, cH = 8, cD = 64;
constexpr int cM = cB * cN;        // 32768 tokens
constexpr int cHD = cH * cD;       // 512
constexpr int cBH = cB * cH;       // 32
constexpr float kEPS = 1e-6f;

// ---- split f32 -> (bf16 hi by truncation, bf16 lo of remainder) ----
__device__ __forceinline__ void split2(float f, ushort& h, ushort& l) {
  unsigned u = __float_as_uint(f);
  h = (ushort)(u >> 16);
  float fl = f - __uint_as_float(u & 0xffff0000u);
  l = (ushort)(__float_as_uint(fl) >> 16);
}
__device__ __forceinline__ int pack_hi(float a, float b) {
  return (int)((__float_as_uint(a) >> 16) | (__float_as_uint(b) & 0xffff0000u));
}
__device__ __forceinline__ int pack_lo(float a, float b) {
  float la = a - __uint_as_float(__float_as_uint(a) & 0xffff0000u);
  float lb = b - __uint_as_float(__float_as_uint(b) & 0xffff0000u);
  return (int)((__float_as_uint(la) >> 16) | (__float_as_uint(lb) & 0xffff0000u));
}

// ---------------- W splitter: f32 -> bf16 hi/lo ----------------
__global__ __launch_bounds__(256) void split_w(const float* __restrict__ src,
    ushort* __restrict__ hi, ushort* __restrict__ lo, int n4) {
  int i = blockIdx.x * 256 + threadIdx.x;
  if (i >= n4) return;
  float4 v = reinterpret_cast<const float4*>(src)[i];
  ushort4 h, l;
  split2(v.x, h.x, l.x); split2(v.y, h.y, l.y);
  split2(v.z, h.z, l.z); split2(v.w, h.w, l.w);
  reinterpret_cast<ushort4*>(hi)[i] = h;
  reinterpret_cast<ushort4*>(lo)[i] = l;
}

// ---------------- split-bf16 MFMA GEMM: C = A[Mx512] @ W[NCx512]^T ----------------
// PRE=false: A is f32, reg-staged + converted (padded LDS).
// PRE=true : A is pre-split bf16 hi/lo, staged via global_load_lds (linear LDS).
// EPI=0: scatter qkv (sigmoid q,k; v*0.125) -> [B,H,N,D] slabs + fused qsum/ksum.
// EPI=1: out = acc + bias.
template<int EPI, bool PRE>
__global__ __launch_bounds__(256) void gemm_mfma(
    const float* __restrict__ A,
    const ushort* __restrict__ Ah_g, const ushort* __restrict__ Al_g,
    const ushort* __restrict__ Wh, const ushort* __restrict__ Wl,
    const float* __restrict__ bias,
    float* __restrict__ o0, float* __restrict__ o1, float* __restrict__ o2,
    float* __restrict__ qsum, float* __restrict__ ksum) {
  constexpr int BM = 128, BN = 128, BK = 32;
  constexpr int LDA = PRE ? 32 : 40;           // pad only the converted path
  __shared__ ushort Ah[BM * LDA], Al[BM * LDA];
  __shared__ ushort Bh[BN * 32], Bl[BN * 32];  // linear (global_load_lds requirement)
  __shared__ float colsum[128];
  const int t = threadIdx.x;
  const int wave = t >> 6, lane = t & 63;
  const int wm = wave >> 1, wn = wave & 1;     // 2x2 waves of 64x64
  const int row0 = blockIdx.x * BM, col0 = blockIdx.y * BN;
  const int l15 = lane & 15, lg = lane >> 4;

  if (EPI == 0 && t < 128) colsum[t] = 0.f;    // ordered by first loop barrier

  f32x4 acc[4][4] = {};

  const int arow = t >> 1, akh = (t & 1) * 16;           // A-stage mapping (f32 path)
  const float* aptr = PRE ? nullptr : (A + (size_t)(row0 + arow) * cC + akh);
  const int brr = lane >> 2, bg = lane & 3;              // 16-B-unit stage mapping

  for (int k0 = 0; k0 < cC; k0 += BK) {
    __syncthreads();
    if (!PRE) {
      // ---- stage A: 16 f32 -> bf16 hi/lo, padded LDS ----
      const float4 fa = *(const float4*)(aptr + k0 + 0);
      const float4 fb = *(const float4*)(aptr + k0 + 4);
      const float4 fc = *(const float4*)(aptr + k0 + 8);
      const float4 fd = *(const float4*)(aptr + k0 + 12);
      int4 H0 = make_int4(pack_hi(fa.x, fa.y), pack_hi(fa.z, fa.w),
                          pack_hi(fb.x, fb.y), pack_hi(fb.z, fb.w));
      int4 H1 = make_int4(pack_hi(fc.x, fc.y), pack_hi(fc.z, fc.w),
                          pack_hi(fd.x, fd.y), pack_hi(fd.z, fd.w));
      int4 L0 = make_int4(pack_lo(fa.x, fa.y), pack_lo(fa.z, fa.w),
                          pack_lo(fb.x, fb.y), pack_lo(fb.z, fb.w));
      int4 L1 = make_int4(pack_lo(fc.x, fc.y), pack_lo(fc.z, fc.w),
                          pack_lo(fd.x, fd.y), pack_lo(fd.z, fd.w));
      *reinterpret_cast<int4*>(&Ah[arow * LDA + akh]) = H0;
      *reinterpret_cast<int4*>(&Ah[arow * LDA + akh + 8]) = H1;
      *reinterpret_cast<int4*>(&Al[arow * LDA + akh]) = L0;
      *reinterpret_cast<int4*>(&Al[arow * LDA + akh + 8]) = L1;
    } else {
      // ---- stage A: global_load_lds dwordx4, hi & lo ----
      #pragma unroll
      for (int hh = 0; hh < 2; ++hh) {
        const int ar = wave * 32 + hh * 16 + brr;
        const size_t goff = (size_t)(row0 + ar) * cC + k0 + bg * 8;
        __builtin_amdgcn_global_load_lds(
            (const __attribute__((address_space(1))) void*)(Ah_g + goff),
            (__attribute__((address_space(3))) void*)(&Ah[(wave * 32 + hh * 16) * 32]),
            16, 0, 0);
        __builtin_amdgcn_global_load_lds(
            (const __attribute__((address_space(1))) void*)(Al_g + goff),
            (__attribute__((address_space(3))) void*)(&Al[(wave * 32 + hh * 16) * 32]),
            16, 0, 0);
      }
    }
    // ---- stage B: global_load_lds dwordx4, hi & lo ----
    #pragma unroll
    for (int hh = 0; hh < 2; ++hh) {
      const int br = wave * 32 + hh * 16 + brr;
      const size_t goff = (size_t)(col0 + br) * cC + k0 + bg * 8;
      __builtin_amdgcn_global_load_lds(
          (const __attribute__((address_space(1))) void*)(Wh + goff),
          (__attribute__((address_space(3))) void*)(&Bh[(wave * 32 + hh * 16) * 32]),
          16, 0, 0);
      __builtin_amdgcn_global_load_lds(
          (const __attribute__((address_space(1))) void*)(Wl + goff),
          (__attribute__((address_space(3))) void*)(&Bl[(wave * 32 + hh * 16) * 32]),
          16, 0, 0);
    }
    __syncthreads();
    // ---- fragments + 3-product MFMA ----
    short8 ah[4], al[4];
    #pragma unroll
    for (int mi = 0; mi < 4; ++mi) {
      const int r = wm * 64 + mi * 16 + l15;
      ah[mi] = *reinterpret_cast<const short8*>(&Ah[r * LDA + lg * 8]);
      al[mi] = *reinterpret_cast<const short8*>(&Al[r * LDA + lg * 8]);
    }
    #pragma unroll
    for (int ni = 0; ni < 4; ++ni) {
      const int c = wn * 64 + ni * 16 + l15;
      const short8 bh = *reinterpret_cast<const short8*>(&Bh[c * 32 + lg * 8]);
      const short8 bl = *reinterpret_cast<const short8*>(&Bl[c * 32 + lg * 8]);
      #pragma unroll
      for (int mi = 0; mi < 4; ++mi) {
        acc[mi][ni] = __builtin_amdgcn_mfma_f32_16x16x32_bf16(ah[mi], bh, acc[mi][ni], 0, 0, 0);
        acc[mi][ni] = __builtin_amdgcn_mfma_f32_16x16x32_bf16(al[mi], bh, acc[mi][ni], 0, 0, 0);
        acc[mi][ni] = __builtin_amdgcn_mfma_f32_16x16x32_bf16(ah[mi], bl, acc[mi][ni], 0, 0, 0);
      }
    }
  }
  // ---- epilogue: C/D map col=lane&15, row=(lane>>4)*4+r ----
  const bool qk_block = (EPI == 0) && (blockIdx.y < 8);
  float csum[4] = {};
  #pragma unroll
  for (int mi = 0; mi < 4; ++mi) {
    #pragma unroll
    for (int ni = 0; ni < 4; ++ni) {
      const int col = col0 + wn * 64 + ni * 16 + l15;
      #pragma unroll
      for (int r = 0; r < 4; ++r) {
        const int m = row0 + wm * 64 + mi * 16 + lg * 4 + r;
        const float val = acc[mi][ni][r];
        if (EPI == 0) {
          const int which = col >> 9;
          const int c2 = col & 511;
          const int h = c2 >> 6, d = c2 & 63;
          const int bb = m >> 13, n = m & 8191;
          const size_t idx = (((size_t)(bb * cH + h)) * cN + n) * cD + d;
          if (which < 2) {
            const float sv = 1.f / (1.f + __expf(-val));
            if (which == 0) o0[idx] = sv; else o1[idx] = sv;
            csum[ni] += sv;
          } else {
            o2[idx] = val * 0.125f;
          }
        } else {
          o0[(size_t)m * cC + col] = val + bias[col];
        }
      }
    }
  }
  if (qk_block) {
    #pragma unroll
    for (int ni = 0; ni < 4; ++ni)
      atomicAdd(&colsum[wn * 64 + ni * 16 + l15], csum[ni]);
    __syncthreads();
    if (t < 128) {
      const int col = col0 + t;
      const int c2 = col & 511;
      const int h = c2 >> 6, d = c2 & 63;
      const int bb = row0 >> 13;
      float* tgt = (col < 512) ? qsum : ksum;
      atomicAdd(&tgt[(bb * cH + h) * cD + d], colsum[t]);
    }
  }
}

// ---------------- K34: si, so; accumulate Sq, Sk (4 rows/wave/iter, float4) ----------------
__global__ __launch_bounds__(256) void k34_flow(const float* __restrict__ q,
      const float* __restrict__ k, const float* __restrict__ qsum,
      const float* __restrict__ ksum, float* __restrict__ si,
      float* __restrict__ Sq, float* __restrict__ Sk) {
  const int bh = blockIdx.x;
  const int n0 = blockIdx.y * 256;
  const int t = threadIdx.x;
  const int wave = t >> 6, lane = t & 63;
  const int g = lane >> 4, j = lane & 15;
  const float* qb = q + (size_t)bh * cN * cD;
  const float* kb = k + (size_t)bh * cN * cD;
  const float4 ks4 = *(const float4*)&ksum[bh * 64 + j * 4];
  const float4 qs4 = *(const float4*)&qsum[bh * 64 + j * 4];
  const float ksd[4] = {ks4.x + kEPS, ks4.y + kEPS, ks4.z + kEPS, ks4.w + kEPS};
  const float qsd[4] = {qs4.x + kEPS, qs4.y + kEPS, qs4.z + kEPS, qs4.w + kEPS};
  float aSq[4] = {}, aSk[4] = {};
  for (int i = 0; i < 16; ++i) {
    const int n = n0 + wave * 64 + i * 4 + g;
    const float4 q4 = *(const float4*)&qb[(size_t)n * cD + j * 4];
    const float4 k4 = *(const float4*)&kb[(size_t)n * cD + j * 4];
    const float qa[4] = {q4.x, q4.y, q4.z, q4.w};
    const float ka[4] = {k4.x, k4.y, k4.z, k4.w};
    float t1 = 0.f, t2 = 0.f;
    #pragma unroll
    for (int c = 0; c < 4; ++c) {
      t1 = fmaf(qa[c] + kEPS, ksd[c], t1);
      t2 = fmaf(ka[c] + kEPS, qsd[c], t2);
    }
    #pragma unroll
    for (int off = 1; off < 16; off <<= 1) {
      t1 += __shfl_xor(t1, off);
      t2 += __shfl_xor(t2, off);
    }
    const float si_n = 1.f / (t1 + kEPS);
    const float so_n = 1.f / (t2 + kEPS);
    if (j == 0) si[(size_t)bh * cN + n] = si_n;
    #pragma unroll
    for (int c = 0; c < 4; ++c) {
      aSq[c] = fmaf(qa[c], si_n, aSq[c]);
      aSk[c] = fmaf(ka[c], so_n, aSk[c]);
    }
  }
  // reduce across the 4 row-groups (lanes 16 apart hold same d)
  #pragma unroll
  for (int c = 0; c < 4; ++c) {
    aSq[c] += __shfl_xor(aSq[c], 16); aSq[c] += __shfl_xor(aSq[c], 32);
    aSk[c] += __shfl_xor(aSk[c], 16); aSk[c] += __shfl_xor(aSk[c], 32);
  }
  __shared__ float sAq[4][64], sAk[4][64];
  if (g == 0) {
    #pragma unroll
    for (int c = 0; c < 4; ++c) { sAq[wave][j * 4 + c] = aSq[c]; sAk[wave][j * 4 + c] = aSk[c]; }
  }
  __syncthreads();
  if (t < 64) {
    atomicAdd(&Sq[bh * 64 + t], sAq[0][t] + sAq[1][t] + sAq[2][t] + sAq[3][t]);
    atomicAdd(&Sk[bh * 64 + t], sAk[0][t] + sAk[1][t] + sAk[2][t] + sAk[3][t]);
  }
}

// ---------------- K45: ev inline; kv' = sum_n (k*ev) (x) v ; Z ----------------
__global__ __launch_bounds__(256) void k45_kv(const float* __restrict__ kk_,
      const float* __restrict__ vv, const float* __restrict__ Sq,
      float* __restrict__ kvout, float* __restrict__ Zb) {
  const int bh = blockIdx.x;
  constexpr int ROWS = cN / 16;
  const int n0 = blockIdx.y * ROWS;
  const int t = threadIdx.x;
  const int d = t & 63;
  const int eb = t >> 6;
  const int rdot = t >> 5, jd = t & 31;      // ev-dot mapping: 8 rows x 32 lanes
  const float* kb = kk_ + (size_t)bh * cN * cD;
  const float* vb = vv + (size_t)bh * cN * cD;
  const float2 Sq2 = *(const float2*)&Sq[bh * 64 + jd * 2];
  const float SqE0 = Sq2.x + kEPS, SqE1 = Sq2.y + kEPS;
  __shared__ float ks[8][64];
  __shared__ float vs[8][64];
  __shared__ float evs[8];
  float acc[16] = {};
  float zacc = 0.f;
  for (int r0 = 0; r0 < ROWS; r0 += 8) {
    __syncthreads();
    {
      const int r = t >> 6, c = t & 63;
      ks[r][c]     = kb[(size_t)(n0 + r0 + r) * cD + c];
      ks[r + 4][c] = kb[(size_t)(n0 + r0 + r + 4) * cD + c];
      vs[r][c]     = vb[(size_t)(n0 + r0 + r) * cD + c];
      vs[r + 4][c] = vb[(size_t)(n0 + r0 + r + 4) * cD + c];
    }
    __syncthreads();
    {
      float tt = fmaf(ks[rdot][jd * 2] + kEPS, SqE0,
                      (ks[rdot][jd * 2 + 1] + kEPS) * SqE1);
      #pragma unroll
      for (int off = 1; off < 32; off <<= 1) tt += __shfl_xor(tt, off);
      if (jd == 0) {
        float cs = fminf(fmaxf(tt + kEPS, -1.f), 1.f);
        evs[rdot] = __expf(cs);
      }
    }
    __syncthreads();
    if (t == 0)
      zacc += evs[0] + evs[1] + evs[2] + evs[3] + evs[4] + evs[5] + evs[6] + evs[7];
    #pragma unroll
    for (int r = 0; r < 8; ++r) {
      const float kd = ks[r][d] * evs[r];
      #pragma unroll
      for (int j2 = 0; j2 < 16; ++j2)
        acc[j2] = fmaf(kd, vs[r][eb * 16 + j2], acc[j2]);
    }
  }
  float* kvb = kvout + (size_t)bh * cD * cD + (size_t)d * cD + eb * 16;
  #pragma unroll
  for (int j2 = 0; j2 < 16; ++j2) atomicAdd(&kvb[j2], acc[j2]);
  if (t == 0) atomicAdd(&Zb[bh], zacc);
}

// ---------------- K6b: xu = (q @ kv*(N/Z)) * si * sa -> split bf16 [M][512] ----------------
__global__ __launch_bounds__(256) void k6b_xu(const float* __restrict__ q,
      const float* __restrict__ kvmat, const float* __restrict__ si,
      const float* __restrict__ Sk, const float* __restrict__ Zb,
      ushort* __restrict__ xh, ushort* __restrict__ xl) {
  const int bh = blockIdx.x;
  const int b = bh >> 3, head = bh & 7;
  const int n0 = blockIdx.y * 64;
  const int lane = threadIdx.x & 63;
  const int wave = threadIdx.x >> 6;
  __shared__ float kvs[64][64];
  const float zs = (float)cN / Zb[bh];
  for (int i = threadIdx.x; i < 4096; i += 256)
    kvs[i >> 6][i & 63] = kvmat[(size_t)bh * 4096 + i] * zs;
  const float SkE = Sk[bh * 64 + lane] + kEPS;
  __syncthreads();
  const float* qb = q + (size_t)bh * cN * cD;
  for (int i = 0; i < 16; ++i) {
    const int n = n0 + wave * 16 + i;
    const float qd = qb[(size_t)n * cD + lane];
    // sa = sigmoid( sum_d (q+eps)*(Sk+eps) + eps )
    float t2 = (qd + kEPS) * SkE;
    #pragma unroll
    for (int off = 1; off < 64; off <<= 1) t2 += __shfl_xor(t2, off);
    const float sa_n = 1.f / (1.f + __expf(-(t2 + kEPS)));
    float a0 = 0.f, a1 = 0.f, a2 = 0.f, a3 = 0.f;
    #pragma unroll
    for (int dd = 0; dd < 64; dd += 4) {
      a0 = fmaf(__shfl(qd, dd),     kvs[dd][lane],     a0);
      a1 = fmaf(__shfl(qd, dd + 1), kvs[dd + 1][lane], a1);
      a2 = fmaf(__shfl(qd, dd + 2), kvs[dd + 2][lane], a2);
      a3 = fmaf(__shfl(qd, dd + 3), kvs[dd + 3][lane], a3);
    }
    const float s = si[(size_t)bh * cN + n] * sa_n;
    const float val = ((a0 + a1) + (a2 + a3)) * s;
    ushort hbits, lbits;
    split2(val, hbits, lbits);
    const size_t m = (size_t)b * cN + n;
    xh[m * cC + head * 64 + lane] = hbits;
    xl[m * cC + head * 64 + lane] = lbits;
  }
}

extern "C" void kernel_launch(void* const* d_in, const int* in_sizes, int n_in,
                              void* d_out, int out_size, void* d_ws, size_t ws_size,
                              hipStream_t stream) {
  (void)in_sizes; (void)n_in; (void)out_size;
  const float* x     = (const float*)d_in[0];
  const float* Wqkv  = (const float*)d_in[1];
  const float* Wproj = (const float*)d_in[2];
  const float* bproj = (const float*)d_in[3];
  float* out = (float*)d_out;
  float* ws  = (float*)d_ws;

  const size_t SLAB = (size_t)cBH * cN * cD;       // 16,777,216 floats
  const size_t OFF_Q   = 0;
  const size_t OFF_K   = SLAB;
  const size_t OFF_V   = 2 * SLAB;                 // xu hi/lo alias v (dead after K45)
  const size_t OFF_ACC = 3 * SLAB;
  const size_t ACC_FLOATS = 2048 * 4 + 32 + (size_t)cBH * cD * cD;
  const size_t OFF_SI  = OFF_ACC + ACC_FLOATS;
  const size_t OFF_SA  = OFF_SI + (size_t)cBH * cN;
  const size_t OFF_EV  = OFF_SA + (size_t)cBH * cN;
  const size_t TOTAL   = OFF_EV + (size_t)cBH * cN;
  if (ws_size < TOTAL * sizeof(float)) return;

  float* q    = ws + OFF_Q;
  float* k    = ws + OFF_K;
  float* v    = ws + OFF_V;
  float* ksum = ws + OFF_ACC;
  float* qsum = ksum + 2048;
  float* Sk   = ksum + 4096;
  float* Sq   = ksum + 6144;
  float* Zb   = ksum + 8192;
  float* kvm  = ksum + 8224;
  float* si   = ws + OFF_SI;

  // xu bf16 hi/lo overlay the v slab (v dead after K45)
  ushort* xh = (ushort*)(ws + OFF_V);
  ushort* xl = xh + (size_t)cM * cHD;

  // W splits alias the si region (wq dead after gemm0, before K34 writes si;
  // wp written after k6b has consumed si)
  ushort* wqh = (ushort*)(ws + OFF_SI);
  ushort* wql = wqh + (size_t)3 * cHD * cC;
  ushort* wph = (ushort*)(ws + OFF_SI);
  ushort* wpl = wph + (size_t)cC * cHD;

  hipMemsetAsync(ksum, 0, ACC_FLOATS * sizeof(float), stream);

  split_w<<<(3 * cHD * cC / 4 + 255) / 256, 256, 0, stream>>>(Wqkv, wqh, wql, 3 * cHD * cC / 4);
  gemm_mfma<0, false><<<dim3(cM / 128, (3 * cHD) / 128), 256, 0, stream>>>(
      x, nullptr, nullptr, wqh, wql, nullptr, q, k, v, qsum, ksum);
  k34_flow<<<dim3(cBH, cN / 256), 256, 0, stream>>>(q, k, qsum, ksum, si, Sq, Sk);
  k45_kv<<<dim3(cBH, 16), 256, 0, stream>>>(k, v, Sq, kvm, Zb);
  k6b_xu<<<dim3(cBH, cN / 64), 256, 0, stream>>>(q, kvm, si, Sk, Zb, xh, xl);
  split_w<<<(cC * cHD / 4 + 255) / 256, 256, 0, stream>>>(Wproj, wph, wpl, cC * cHD / 4);
  gemm_mfma<1, true><<<dim3(cM / 128, cHD / 128), 256, 0, stream>>>(
      nullptr, xh, xl, wph, wpl, bproj, out, nullptr, nullptr, nullptr, nullptr);
}